// Round 4
// baseline (743.470 us; speedup 1.0000x reference)
//
#include <hip/hip_runtime.h>
#include <hip/hip_bf16.h>

#define RES   100
#define ITERS 1000
#define SLOTP 128            // floats per LDS boundary-row slot

typedef float vf2 __attribute__((ext_vector_type(2)));

// ---------------- fused MLP layers 1-3 ----------------
__global__ __launch_bounds__(256) void mlp123(const float* __restrict__ pores,
                                              const float* __restrict__ W1, const float* __restrict__ b1,
                                              const float* __restrict__ W2, const float* __restrict__ b2,
                                              const float* __restrict__ W3, const float* __restrict__ b3,
                                              float* __restrict__ x3out) {
    __shared__ float x1[128];
    __shared__ float x2[256];
    const int s = blockIdx.x, tid = threadIdx.x;

    if (tid < 128) {
        float acc = b1[tid];
#pragma unroll
        for (int k = 0; k < 25; ++k)
            acc = fmaf(pores[s * 25 + k], W1[k * 128 + tid], acc);
        x1[tid] = fmaxf(acc, 0.0f);
    }
    __syncthreads();

    {
        float acc = b2[tid];
#pragma unroll 8
        for (int k = 0; k < 128; ++k)
            acc = fmaf(x1[k], W2[k * 256 + tid], acc);
        x2[tid] = fmaxf(acc, 0.0f);
    }
    __syncthreads();

    {
        float a0 = b3[tid], a1 = b3[tid + 256];
#pragma unroll 8
        for (int k = 0; k < 256; ++k) {
            float xv = x2[k];
            a0 = fmaf(xv, W3[k * 512 + tid],       a0);
            a1 = fmaf(xv, W3[k * 512 + tid + 256], a1);
        }
        x3out[s * 512 + tid]       = fmaxf(a0, 0.0f);
        x3out[s * 512 + tid + 256] = fmaxf(a1, 0.0f);
    }
}

// ---------------- layer 4: gen + residual + clamp, ILP-pipelined ----------------
__global__ __launch_bounds__(256) void fc4_fused(const float* __restrict__ X3,
                                                 const float* __restrict__ W4,
                                                 const float* __restrict__ b4,
                                                 const float* __restrict__ pores,
                                                 float* __restrict__ cond) {
    const int j = blockIdx.x * 256 + threadIdx.x;
    if (j >= RES * RES) return;
    const int bg = blockIdx.y;
    const float* x = X3 + bg * 8 * 512;

    float acc[8];
    float bj = b4[j];
#pragma unroll
    for (int b = 0; b < 8; ++b) acc[b] = bj;

    for (int k0 = 0; k0 < 512; k0 += 8) {
        float w[8];
#pragma unroll
        for (int u = 0; u < 8; ++u)
            w[u] = W4[(k0 + u) * (RES * RES) + j];
#pragma unroll
        for (int u = 0; u < 8; ++u) {
#pragma unroll
            for (int b = 0; b < 8; ++b)
                acc[b] = fmaf(x[b * 512 + k0 + u], w[u], acc[b]);
        }
    }

    const int row = j / RES, col = j % RES;
    const int p = (row / 20) * 5 + (col / 20);
#pragma unroll
    for (int b = 0; b < 8; ++b) {
        int bb = bg * 8 + b;
        float base = 1.0f - pores[bb * 25 + p];
        cond[bb * RES * RES + j] = fmaxf(acc[b] + base, 0.01f);
    }
}

// ---------------- Jacobi solve: DPP + forced v_pk_fma_f32 ----------------
__device__ __forceinline__ float dpp_shr1(float old_v, float src) {  // lane i <- src[i-1]
    return __int_as_float(__builtin_amdgcn_update_dpp(
        __float_as_int(old_v), __float_as_int(src), 0x138, 0xf, 0xf, false));
}
__device__ __forceinline__ float dpp_shl1(float old_v, float src) {  // lane i <- src[i+1]
    return __int_as_float(__builtin_amdgcn_update_dpp(
        __float_as_int(old_v), __float_as_int(src), 0x130, 0xf, 0xf, false));
}
__device__ __forceinline__ vf2 pk_mul(vf2 a, vf2 b) {
    vf2 d; asm("v_pk_mul_f32 %0, %1, %2" : "=v"(d) : "v"(a), "v"(b)); return d;
}
__device__ __forceinline__ vf2 pk_fma(vf2 a, vf2 b, vf2 c) {
    vf2 d; asm("v_pk_fma_f32 %0, %1, %2, %3" : "=v"(d) : "v"(a), "v"(b), "v"(c)); return d;
}

// per row: WP = {west-of-lo, west-of-hi} = {dpp_shr(hi) [lane0->lo], lo}
//          EP = {east-of-lo, east-of-hi} = {hi, dpp_shl(lo) [lane49->hi]}
// Tnew = wN*nb + wS*sb + wW*WP + wE*EP   (4 packed VOP3P ops)
template<int R>
__device__ __forceinline__ void jstep(const vf2* __restrict__ nptr, const vf2* __restrict__ sptr,
                                      vf2* __restrict__ topptr, vf2* __restrict__ botptr,
                                      const vf2* wN, const vf2* wS,
                                      const vf2* wW, const vf2* wE,
                                      const vf2* Tin, vf2* Tout, bool fix49) {
    vf2 nval = *nptr;          // LDS reads issued first, consumed last
    vf2 sval = *sptr;

    // middle rows: register-only neighbors (hide LDS latency)
#pragma unroll
    for (int r = 1; r < R - 1; ++r) {
        float lo = Tin[r].x, hi = Tin[r].y;
        vf2 WP, EP;
        WP.x = dpp_shr1(lo, hi);  WP.y = lo;
        float e = dpp_shl1(hi, lo);
        EP.x = hi;  EP.y = fix49 ? hi : e;
        vf2 acc = pk_mul(wN[r], Tin[r - 1]);
        acc = pk_fma(wS[r], Tin[r + 1], acc);
        acc = pk_fma(wW[r], WP, acc);
        acc = pk_fma(wE[r], EP, acc);
        Tout[r] = acc;
    }
    // row 0 (uses nval)
    {
        float lo = Tin[0].x, hi = Tin[0].y;
        vf2 WP, EP;
        WP.x = dpp_shr1(lo, hi);  WP.y = lo;
        float e = dpp_shl1(hi, lo);
        EP.x = hi;  EP.y = fix49 ? hi : e;
        vf2 acc = pk_mul(wN[0], nval);
        acc = pk_fma(wS[0], Tin[1], acc);
        acc = pk_fma(wW[0], WP, acc);
        acc = pk_fma(wE[0], EP, acc);
        Tout[0] = acc;
        *topptr = acc;
    }
    // row R-1 (uses sval)
    {
        float lo = Tin[R - 1].x, hi = Tin[R - 1].y;
        vf2 WP, EP;
        WP.x = dpp_shr1(lo, hi);  WP.y = lo;
        float e = dpp_shl1(hi, lo);
        EP.x = hi;  EP.y = fix49 ? hi : e;
        vf2 acc = pk_mul(wN[R - 1], Tin[R - 2]);
        acc = pk_fma(wS[R - 1], sval, acc);
        acc = pk_fma(wW[R - 1], WP, acc);
        acc = pk_fma(wE[R - 1], EP, acc);
        Tout[R - 1] = acc;
        *botptr = acc;
    }
}

__global__ __launch_bounds__(1024) void jacobi(const float* __restrict__ cond,
                                               float* __restrict__ kappa_out) {
    __shared__ float kst[RES * RES];
    __shared__ float SA[34 * SLOTP];
    __shared__ float SB[34 * SLOTP];

    const int b   = blockIdx.x;
    const int tid = threadIdx.x;

    for (int i = tid; i < RES * RES; i += 1024)
        kst[i] = cond[b * RES * RES + i];
    if (tid < SLOTP) {
        SA[32 * SLOTP + tid] = 1.0f;  SA[33 * SLOTP + tid] = 0.0f;
        SB[32 * SLOTP + tid] = 1.0f;  SB[33 * SLOTP + tid] = 0.0f;
    }
    __syncthreads();

    const int w    = tid >> 6;
    const int lane = tid & 63;
    const int R    = (w < 4) ? 7 : 6;
    const int r0   = (w < 4) ? 7 * w : 28 + 6 * (w - 4);
    const int c0   = min(2 * lane, 98), c1 = c0 + 1;
    const int lane2 = 2 * lane;
    const bool fix49 = (lane == 49);

    vf2 wN[7], wS[7], wW[7], wE[7], T0[7], T1[7];

#pragma unroll
    for (int r = 0; r < 7; ++r) {
        if (r < R) {
            int i   = r0 + r;
            int in_ = i ? i - 1 : 0;
            int is_ = (i < RES - 1) ? i + 1 : RES - 1;
            int jw  = c0 ? c0 - 1 : 0;
            int je  = (c1 < RES - 1) ? c1 + 1 : RES - 1;
            float kc0 = kst[i * RES + c0], kc1 = kst[i * RES + c1];
            float kn0 = 0.5f * (kc0 + kst[in_ * RES + c0]);
            float kn1 = 0.5f * (kc1 + kst[in_ * RES + c1]);
            float ks0 = 0.5f * (kc0 + kst[is_ * RES + c0]);
            float ks1 = 0.5f * (kc1 + kst[is_ * RES + c1]);
            float kw0 = 0.5f * (kc0 + kst[i * RES + jw]);
            float kw1 = 0.5f * (kc1 + kc0);
            float ke0 = 0.5f * (kc0 + kc1);
            float ke1 = 0.5f * (kc1 + kst[i * RES + je]);
            float inv0 = 1.0f / (kn0 + ks0 + kw0 + ke0 + 1e-12f);
            float inv1 = 1.0f / (kn1 + ks1 + kw1 + ke1 + 1e-12f);
            wN[r].x = kn0 * inv0;  wN[r].y = kn1 * inv1;
            wS[r].x = ks0 * inv0;  wS[r].y = ks1 * inv1;
            wW[r].x = kw0 * inv0;  wW[r].y = kw1 * inv1;
            wE[r].x = ke0 * inv0;  wE[r].y = ke1 * inv1;
            float v = 1.0f - (float)i * (1.0f / (RES - 1));
            T0[r].x = v;  T0[r].y = v;
        }
    }

    // publish initial boundary rows into SA
    vf2 bot0 = (w < 4) ? T0[6] : T0[5];
    *(vf2*)(SA + (2 * w) * SLOTP + lane2)     = T0[0];
    *(vf2*)(SA + (2 * w + 1) * SLOTP + lane2) = bot0;
    __syncthreads();

    const int nslot = (w == 0)  ? 32 : (2 * w - 1);
    const int sslot = (w == 15) ? 33 : (2 * w + 2);
    const int topsl = 2 * w;

    const vf2* SAn = (const vf2*)(SA + nslot * SLOTP + lane2);
    const vf2* SAs = (const vf2*)(SA + sslot * SLOTP + lane2);
    const vf2* SBn = (const vf2*)(SB + nslot * SLOTP + lane2);
    const vf2* SBs = (const vf2*)(SB + sslot * SLOTP + lane2);
    vf2* SAtop = (vf2*)(SA + topsl * SLOTP + lane2);
    vf2* SAbot = (vf2*)(SA + (topsl + 1) * SLOTP + lane2);
    vf2* SBtop = (vf2*)(SB + topsl * SLOTP + lane2);
    vf2* SBbot = (vf2*)(SB + (topsl + 1) * SLOTP + lane2);

    for (int it = 0; it < ITERS / 2; ++it) {
        if (w < 4) jstep<7>(SAn, SAs, SBtop, SBbot, wN, wS, wW, wE, T0, T1, fix49);
        else       jstep<6>(SAn, SAs, SBtop, SBbot, wN, wS, wW, wE, T0, T1, fix49);
        __syncthreads();
        if (w < 4) jstep<7>(SBn, SBs, SAtop, SAbot, wN, wS, wW, wE, T1, T0, fix49);
        else       jstep<6>(SBn, SBs, SAtop, SAbot, wN, wS, wW, wE, T1, T0, fix49);
        __syncthreads();
    }

    // kappa = mean_j 2*res*k[0][j]*(1 - T[0][j]) = 2 * sum_lanes k*(1-T)
    if (w == 0) {
        float s = 0.0f;
        if (lane < 50)
            s = kst[c0] * (1.0f - T0[0].x) + kst[c1] * (1.0f - T0[0].y);
        for (int off = 32; off; off >>= 1)
            s += __shfl_down(s, off);
        if (lane == 0) kappa_out[b] = 2.0f * s;
    }
}

extern "C" void kernel_launch(void* const* d_in, const int* in_sizes, int n_in,
                              void* d_out, int out_size, void* d_ws, size_t ws_size,
                              hipStream_t stream) {
    (void)in_sizes; (void)n_in; (void)out_size; (void)ws_size;
    const float* pores = (const float*)d_in[0];
    const float* W1 = (const float*)d_in[1];
    const float* b1 = (const float*)d_in[2];
    const float* W2 = (const float*)d_in[3];
    const float* b2 = (const float*)d_in[4];
    const float* W3 = (const float*)d_in[5];
    const float* b3 = (const float*)d_in[6];
    const float* W4 = (const float*)d_in[7];
    const float* b4 = (const float*)d_in[8];

    float* x3 = (float*)d_ws;               // 32*512

    float* kappa = (float*)d_out;           // 32
    float* cond  = kappa + 32;              // 32*100*100

    mlp123<<<32, 256, 0, stream>>>(pores, W1, b1, W2, b2, W3, b3, x3);
    fc4_fused<<<dim3(40, 4), 256, 0, stream>>>(x3, W4, b4, pores, cond);
    jacobi<<<32, 1024, 0, stream>>>(cond, kappa);
}